// Round 6
// baseline (8930.585 us; speedup 1.0000x reference)
//
#include <hip/hip_runtime.h>

// ---------------------------------------------------------------------------
// 2-layer LSTM (B=256, T=784, H=512, C=10), persistent kernel, round 6.
//
// Round-5 post-mortem: 10.9us/step, MfmaUtil 5.8%. The hard 64-WG join per
// phase (arrive-all + poll-all-flags) dominates: max-over-64 tail + flag
// flight + poll detection, plus poll contention (64 WGs x 64 lanes hammering
// 2 cache lines; FETCH ~3.1MB/phase matches poll traffic).
//
// Round-6: decoupled populations + aggregated counters.
//   - Per group (rb = 64 batch rows): two monotone counters cnt1 (L1 pop),
//     cnt2 (L2 pop). arrive = ONE fire-and-forget device-scope atomicAdd
//     (executes at the coherence point; ordered after data by the explicit
//     vmcnt(0) drain). wait = ONE lane polling a single 4B word for
//     cnt >= 32*phase. No per-WG flags, no 64-lane polls.
//   - Populations decoupled: L1@k waits {cnt1>=32k, cnt2>=32(k-1)};
//     L2@m waits {cnt2>=32m, cnt1>=32m}. L1's phase is lighter -> it runs
//     ~1 phase ahead, so L2's c1 dependency is pre-satisfied; steady-state
//     period = L2 chain alone, no join tail.
//   - Buffers deepened for the slack: c1[4], h2[4], h1[2].
//   - FC (out_duty, t=k-3) moved AFTER L1's arrive -> off critical chain.
//
// Dependency audit (L1@k computes step t=k; L2@m computes step t=m-1):
//   L1@k reads  h1[(k-1)&1] <- L1 peers @k-1          (cnt1>=32k)
//   L1@k writes h1[k&1] (last read @k-1 by L1 peers)   (cnt1>=32k)
//        writes c1[k&3] (prev write @k-4, last read by L2@k-3;
//                        gated by cnt2>=32(k-1) => L2 completed k-2 ✓)
//   L1@k out_duty(t=k-3) reads h2[t&3] <- L2@k-2       (cnt2>=32(k-1))
//   L2@m reads  h2[(m-2)&3] <- L2 peers @m-1           (cnt2>=32m)
//        reads  c1[(m-1)&3] <- L1@m-1                  (cnt1>=32m)
//        writes h2[(m-1)&3] (prev write @m-4, last readers: L2@m-3 peers
//                        (cnt2>=32m ✓) and L1 out_duty@m-2, which precedes
//                        L1 arrive(m) in program order => cnt1>=32m ✓)
//   Coherence: all slab data via sc0/sc1 cache-bypass asm ops (validated
//   rounds 3-5); vmcnt(0) drain before every arrive.
// ---------------------------------------------------------------------------

constexpr int Bn = 256;   // batch
constexpr int Tn = 784;   // timesteps
constexpr int Hn = 512;   // hidden
constexpr int Cn = 10;    // classes

typedef short s16x8 __attribute__((ext_vector_type(8)));
typedef float f32x4 __attribute__((ext_vector_type(4)));

__device__ __forceinline__ unsigned short f2bf(float f) {
  unsigned u = __float_as_uint(f);
  u += 0x7FFFu + ((u >> 16) & 1u);  // round-to-nearest-even
  return (unsigned short)(u >> 16);
}
__device__ __forceinline__ float bf2f(unsigned short s) {
  return __uint_as_float(((unsigned)s) << 16);
}
__device__ __forceinline__ float sigm(float v) { return 1.f / (1.f + __expf(-v)); }
__device__ __forceinline__ float tanh_(float v) {
  float vc = fminf(fmaxf(v, -15.f), 15.f);
  float e = __expf(2.f * vc);
  return (e - 1.f) / (e + 1.f);
}

// ---- system-scope (cache-bypassing) accessors ----
__device__ __forceinline__ s16x8 load16_sc(const unsigned short* p) {
  s16x8 r;
  asm volatile("global_load_dwordx4 %0, %1, off sc0 sc1"
               : "=v"(r) : "v"(p) : "memory");
  return r;
}
__device__ __forceinline__ void store2_sc(unsigned short* p, unsigned short v) {
  unsigned w = v;
  asm volatile("global_store_short %0, %1, off sc0 sc1"
               :: "v"(p), "v"(w) : "memory");
}
__device__ __forceinline__ void store4_sc(float* p, float v) {
  asm volatile("global_store_dword %0, %1, off sc0 sc1"
               :: "v"(p), "v"(v) : "memory");
}
// Drain all outstanding vmem (HW counter covers inline-asm ops) + pin sched.
__device__ __forceinline__ void vm0_fence() {
  asm volatile("s_waitcnt vmcnt(0)" ::: "memory");
  __builtin_amdgcn_sched_barrier(0);
}

// ---- counter-based sync ----
// arrive: drain all waves' sc data stores, then lane 0 fires one atomicAdd
// (device scope, executes at the coherence point; no ack needed).
__device__ __forceinline__ void arrive_cnt(unsigned* p) {
  vm0_fence();
  __syncthreads();
  if (threadIdx.x == 0) atomicAdd(p, 1u);
}
// wait: single lane polls two 4B counters (both loads in flight together).
__device__ __forceinline__ void wait2c(const unsigned* pA, int thA,
                                       const unsigned* pB, int thB) {
  if (threadIdx.x == 0 && (thA > 0 || thB > 0)) {
    int guard = 0;
    for (;;) {
      unsigned a, b;
      asm volatile("global_load_dword %0, %2, off sc0 sc1\n\t"
                   "global_load_dword %1, %3, off sc0 sc1\n\t"
                   "s_waitcnt vmcnt(0)"
                   : "=&v"(a), "=&v"(b) : "v"(pA), "v"(pB) : "memory");
      if ((int)a >= thA && (int)b >= thB) break;
      if (++guard > (1 << 20)) break;  // deadlock escape only
      __builtin_amdgcn_s_sleep(1);
    }
  }
  __syncthreads();
}

// 64x(4x16) gate-GEMM slice, K=512, 16x16x32 bf16 MFMA (A via sc loads,
// B weight slice in LDS, XOR-swizzled).
__device__ __forceinline__ void gemm_slice(const unsigned short* __restrict__ Abase,
                                           const char* smem, int ldsbase,
                                           f32x4* acc, int l) {
  const int lg = l >> 4, rA = l & 15, lx = l & 7;
  s16x8 af[16];
#pragma unroll
  for (int kc = 0; kc < 16; ++kc)
    af[kc] = load16_sc(Abase + kc * 32);
  vm0_fence();
#pragma unroll
  for (int kc = 0; kc < 16; ++kc) {
#pragma unroll
    for (int g = 0; g < 4; ++g) {
      int byte = ldsbase + (((g << 4) + rA) << 10) + ((((kc << 2) + lg) ^ lx) << 4);
      s16x8 bf = *(const s16x8*)(smem + byte);
      acc[g] = __builtin_amdgcn_mfma_f32_16x16x32_bf16(af[kc], bf, acc[g], 0, 0, 0);
    }
  }
}

// Fused double slice for L2: issue BOTH A-fragment load sets (h2 and c1),
// one vmcnt(0), then both MFMA passes.
__device__ __forceinline__ void gemm2_slice(const unsigned short* __restrict__ A1,
                                            const unsigned short* __restrict__ A2,
                                            const char* smem, f32x4* acc, int l) {
  const int lg = l >> 4, rA = l & 15, lx = l & 7;
  s16x8 a1[16], a2[16];
#pragma unroll
  for (int kc = 0; kc < 16; ++kc) a1[kc] = load16_sc(A1 + kc * 32);
#pragma unroll
  for (int kc = 0; kc < 16; ++kc) a2[kc] = load16_sc(A2 + kc * 32);
  vm0_fence();
#pragma unroll
  for (int kc = 0; kc < 16; ++kc) {
#pragma unroll
    for (int g = 0; g < 4; ++g) {
      int byte = (((g << 4) + rA) << 10) + ((((kc << 2) + lg) ^ lx) << 4);
      acc[g] = __builtin_amdgcn_mfma_f32_16x16x32_bf16(a1[kc], *(const s16x8*)(smem + byte), acc[g], 0, 0, 0);
    }
  }
#pragma unroll
  for (int kc = 0; kc < 16; ++kc) {
#pragma unroll
    for (int g = 0; g < 4; ++g) {
      int byte = 65536 + (((g << 4) + rA) << 10) + ((((kc << 2) + lg) ^ lx) << 4);
      acc[g] = __builtin_amdgcn_mfma_f32_16x16x32_bf16(a2[kc], *(const s16x8*)(smem + byte), acc[g], 0, 0, 0);
    }
  }
}

// Final FC for one timestep column (L1 WGs, after arrive -> off critical path)
__device__ __forceinline__ void out_duty(int tt, int sub, int wv, int l,
                                         const unsigned short* __restrict__ h2buf,
                                         const char* smem, float* __restrict__ out) {
  const int b = (sub << 1) + (wv >> 1);
  const int cg = (wv & 1) * 5;
  s16x8 h8 = load16_sc(h2buf + (size_t)b * Hn + (l << 3));
  vm0_fence();
  const unsigned short* wf = (const unsigned short*)(smem + 65536);
  float rs[5];
#pragma unroll
  for (int c5 = 0; c5 < 5; ++c5) {
    s16x8 w8 = *(const s16x8*)(wf + (size_t)(cg + c5) * Hn + (l << 3));
    float s = 0.f;
#pragma unroll
    for (int i = 0; i < 8; ++i)
      s += bf2f((unsigned short)h8[i]) * bf2f((unsigned short)w8[i]);
    rs[c5] = s;
  }
#pragma unroll
  for (int c5 = 0; c5 < 5; ++c5) {
#pragma unroll
    for (int off = 32; off > 0; off >>= 1)
      rs[c5] += __shfl_xor(rs[c5], off);
  }
  if (l < 5) {
    float v = (l == 0) ? rs[0] : (l == 1) ? rs[1] : (l == 2) ? rs[2] : (l == 3) ? rs[3] : rs[4];
    v += ((const float*)(smem + 65536 + Cn * Hn * 2))[cg + l];
    store4_sc(out + (size_t)b * (Tn * Cn) + (size_t)tt * Cn + (cg + l), v);
  }
}

__global__ void __launch_bounds__(256, 1)
lstm2_kernel(const float* __restrict__ x,
             const float* __restrict__ W_ih1, const float* __restrict__ W_hh1,
             const float* __restrict__ b_ih1, const float* __restrict__ b_hh1,
             const float* __restrict__ W_ih2, const float* __restrict__ W_hh2,
             const float* __restrict__ b_ih2, const float* __restrict__ b_hh2,
             const float* __restrict__ W_fc, const float* __restrict__ b_fc,
             float* __restrict__ out,
             unsigned* __restrict__ cnts,        // per-group counters
             unsigned short* __restrict__ h1b,   // [2][B][H] bf16
             unsigned short* __restrict__ c1b,   // [4][B][H] bf16
             unsigned short* __restrict__ h2b)   // [4][B][H] bf16
{
  extern __shared__ char smem[];
  const int tid = threadIdx.x;
  const int wg = blockIdx.x;
  const int wv = tid >> 6;
  const int l = tid & 63;
  const bool isL1 = (wg < 128);
  const int sub = isL1 ? wg : (wg - 128);
  const int rb = (sub >> 5) << 6;   // 0,64,128,192
  const int js = (sub & 31) << 4;   // 0..496

  // ---- one-time: weight slices -> LDS bf16, XOR-swizzled on 16B chunks ----
  {
    const float* W0 = isL1 ? W_hh1 : W_hh2;
    for (int idx = tid * 4; idx < 64 * 512; idx += 1024) {
      int row = idx >> 9, k = idx & 511;                    // row = g*16 + c
      int n = ((row >> 4) << 9) + js + (row & 15);          // gate col
      float4 w = *(const float4*)(W0 + (size_t)n * Hn + k);
      short4 v = { (short)f2bf(w.x), (short)f2bf(w.y), (short)f2bf(w.z), (short)f2bf(w.w) };
      int byte = (row << 10) + ((((k >> 3) ^ (row & 7)) << 4)) + ((k & 7) << 1);
      *(short4*)(smem + byte) = v;
    }
    if (!isL1) {
      for (int idx = tid * 4; idx < 64 * 512; idx += 1024) {
        int row = idx >> 9, k = idx & 511;
        int n = ((row >> 4) << 9) + js + (row & 15);
        float4 w = *(const float4*)(W_ih2 + (size_t)n * Hn + k);
        short4 v = { (short)f2bf(w.x), (short)f2bf(w.y), (short)f2bf(w.z), (short)f2bf(w.w) };
        int byte = 65536 + (row << 10) + ((((k >> 3) ^ (row & 7)) << 4)) + ((k & 7) << 1);
        *(short4*)(smem + byte) = v;
      }
    } else {
      unsigned short* wf = (unsigned short*)(smem + 65536);
      for (int idx = tid; idx < Cn * Hn; idx += 256) wf[idx] = f2bf(W_fc[idx]);
      if (tid < Cn) ((float*)(smem + 65536 + Cn * Hn * 2))[tid] = b_fc[tid];
    }
  }
  __syncthreads();

  // per-lane constants
  float wih1g[4], b1g[4], b2g[4];
  {
    int col = js + (l & 15);
#pragma unroll
    for (int g = 0; g < 4; ++g) {
      int n = (g << 9) + col;
      if (isL1) { wih1g[g] = W_ih1[n]; b1g[g] = b_ih1[n] + b_hh1[n]; b2g[g] = 0.f; }
      else      { wih1g[g] = 0.f;      b1g[g] = 0.f;                 b2g[g] = b_ih2[n] + b_hh2[n]; }
    }
  }

  const int rA = l & 15, lg = l >> 4;
  const int arow = rb + (wv << 4) + rA;           // A-fragment row (batch)
  const int myrow = rb + (wv << 4) + (lg << 2);   // C/D first row (batch)
  const int colj = js + rA;                       // my hidden col

  // per-group counters: cnt1 at g*64, cnt2 at g*64+16 (separate 64B lines)
  const int g4 = sub >> 5;
  unsigned* c1p = cnts + g4 * 64;
  unsigned* c2p = cnts + g4 * 64 + 16;

  const size_t SLAB = (size_t)Bn * Hn;
  float cst[4] = {0.f, 0.f, 0.f, 0.f};  // persistent cell state (c1 or c2)

  if (isL1) {
    for (int k = 0; k <= Tn + 2; ++k) {
      wait2c(c1p, k << 5, c2p, (k - 1) << 5);
      if (k < Tn) {
        const int t = k;
        float xv[4];
#pragma unroll
        for (int r = 0; r < 4; ++r) xv[r] = x[(size_t)(myrow + r) * Tn + t];
        f32x4 acc[4];
#pragma unroll
        for (int g = 0; g < 4; ++g) acc[g] = f32x4{0.f, 0.f, 0.f, 0.f};
        gemm_slice(h1b + (size_t)((k - 1) & 1) * SLAB + (size_t)arow * Hn + (lg << 3),
                   smem, 0, acc, l);
        unsigned short* h1w = h1b + (size_t)(k & 1) * SLAB;
        unsigned short* c1w = c1b + (size_t)(k & 3) * SLAB;
#pragma unroll
        for (int r = 0; r < 4; ++r) {
          float iv = sigm(acc[0][r] + xv[r] * wih1g[0] + b1g[0]);
          float ff = sigm(acc[1][r] + xv[r] * wih1g[1] + b1g[1]);
          float gv = tanh_(acc[2][r] + xv[r] * wih1g[2] + b1g[2]);
          float ov = sigm(acc[3][r] + xv[r] * wih1g[3] + b1g[3]);
          float c = ff * cst[r] + iv * gv;
          cst[r] = c;
          float h = ov * tanh_(c);
          size_t off = (size_t)(myrow + r) * Hn + colj;
          store2_sc(h1w + off, f2bf(h));
          store2_sc(c1w + off, f2bf(c));
        }
      }
      arrive_cnt(c1p);
      if (k >= 3)   // FC for t=k-3, off the critical chain (after arrive)
        out_duty(k - 3, sub, wv, l, h2b + (size_t)((k - 3) & 3) * SLAB, smem, out);
    }
  } else {
    for (int m = 0; m <= Tn + 1; ++m) {
      wait2c(c2p, m << 5, c1p, m << 5);
      if (m >= 1 && m <= Tn) {
        const int t = m - 1;
        f32x4 acc[4];
#pragma unroll
        for (int g = 0; g < 4; ++g) acc[g] = f32x4{0.f, 0.f, 0.f, 0.f};
        gemm2_slice(h2b + (size_t)((m - 2) & 3) * SLAB + (size_t)arow * Hn + (lg << 3),
                    c1b + (size_t)((m - 1) & 3) * SLAB + (size_t)arow * Hn + (lg << 3),
                    smem, acc, l);
        unsigned short* h2w = h2b + (size_t)(t & 3) * SLAB;
#pragma unroll
        for (int r = 0; r < 4; ++r) {
          float iv = sigm(acc[0][r] + b2g[0]);
          float ff = sigm(acc[1][r] + b2g[1]);
          float gv = tanh_(acc[2][r] + b2g[2]);
          float ov = sigm(acc[3][r] + b2g[3]);
          float c = ff * cst[r] + iv * gv;
          cst[r] = c;
          float h = ov * tanh_(c);
          store2_sc(h2w + (size_t)(myrow + r) * Hn + colj, f2bf(h));
        }
      }
      arrive_cnt(c2p);
    }
  }
}

extern "C" void kernel_launch(void* const* d_in, const int* in_sizes, int n_in,
                              void* d_out, int out_size, void* d_ws, size_t ws_size,
                              hipStream_t stream) {
  const float* x     = (const float*)d_in[0];
  const float* W_ih1 = (const float*)d_in[1];
  const float* W_hh1 = (const float*)d_in[2];
  const float* b_ih1 = (const float*)d_in[3];
  const float* b_hh1 = (const float*)d_in[4];
  const float* W_ih2 = (const float*)d_in[5];
  const float* W_hh2 = (const float*)d_in[6];
  const float* b_ih2 = (const float*)d_in[7];
  const float* b_hh2 = (const float*)d_in[8];
  const float* W_fc  = (const float*)d_in[9];
  const float* b_fc  = (const float*)d_in[10];
  float* out = (float*)d_out;

  unsigned* cnts = (unsigned*)d_ws;
  unsigned short* h1b = (unsigned short*)((char*)d_ws + 4096);
  unsigned short* c1b = h1b + (size_t)2 * Bn * Hn;
  unsigned short* h2b = c1b + (size_t)4 * Bn * Hn;

  // zero counters + state slabs every launch (graph-replay safe)
  size_t zbytes = 4096 + (size_t)(2 + 4 + 4) * Bn * Hn * sizeof(unsigned short);
  hipMemsetAsync(d_ws, 0, zbytes, stream);

  (void)hipFuncSetAttribute((const void*)lstm2_kernel,
                            hipFuncAttributeMaxDynamicSharedMemorySize, 131072);

  lstm2_kernel<<<dim3(256), dim3(256), 131072, stream>>>(
      x, W_ih1, W_hh1, b_ih1, b_hh1, W_ih2, W_hh2, b_ih2, b_hh2, W_fc, b_fc,
      out, cnts, h1b, c1b, h2b);
}

// Round 7
// 7124.772 us; speedup vs baseline: 1.2535x; 1.2535x over previous
//
#include <hip/hip_runtime.h>

// ---------------------------------------------------------------------------
// 2-layer LSTM (B=256, T=784, H=512, C=10), persistent kernel, round 7.
//
// Round-6 post-mortem: four sync designs all floor at ~11us/phase ->
// the phase BODY is the floor, dominated by redundant LDS weight reads
// (each wave re-reads the whole B slice per phase: L2 512 ds_read_b128/WG
// x ~12cyc = 2.6us serial at the CU LDS pipe) + MALL latency chain.
//
// Round-7: weights are loop-invariant -> persist in VGPRs (1 wave/SIMD ->
// ~450-reg budget, we were at 136).
//   - L1 wave: W_hh1 slice in bw[64] (256 VGPR). Zero LDS in the loop.
//   - L2 wave: W_hh2 slice in bw[64] (256 VGPR). W_ih2 gemm DEFERRED:
//     in phase m (after arrive) compute p2 = c1(m)@W_ih2^T (LDS B) into
//     registers; phase m+1 critical path = h2 A-loads + 64 reg-B MFMA +
//     p2 + cell. LDS work fills the wait slack, off the chain.
//   - out_duty h2-fragment load issued immediately after the wait
//     (retired by arrive's drain; consumed after arrive).
//
// Dependency audit (phase-k producers all covered):
//   L1@k:  waits cnt1>=32k, cnt2>=32(k-1).
//     reads h1[(k-1)&1] <- L1@k-1 (cnt1); writes h1[k&1] (WAR: last read
//     @k-1, cnt1); writes c1[k&3] (WAR: last read by L2 deferred@k-1,
//     which precedes L2 arrive@k => cnt2>=32(k-1)... L2 deferred@k-1
//     completes before L2's arrive(k) -> covered by cnt2>=32(k-1)? arrive(k)
//     is published AFTER deferred@k-1 in program order; cnt2>=32(k-1) means
//     arrive(k-1) i.e. deferred@k-2 done -> c1[k&3] last read @k-4+? :
//     c1[k&3] previously written @k-4, read by L2 deferred@k-4 (done before
//     L2 arrive(k-3) <= cnt2>=32(k-1) requires arrive(k-1) >= k-3 ✓).
//     out_duty(k-3) reads h2[(k-3)&3] <- L2@k-2 (cnt2>=32(k-1) ✓);
//     h2 WAR vs L2@k+2 overwrite gated by cnt1>=32(k+2) which needs L1
//     arrive(k+1), i.e. after out_duty(k-3)'s h8 consumed ✓.
//   L2@m:  waits cnt2>=32m, cnt1>=32m (critical);
//          deferred waits cnt1>=32(m+1) (c1(m) by L1@m).
//     critical reads h2[(m-2)&3] <- L2 peers @m-1 (cnt2 ✓) + p2 (own regs);
//     writes h2[(m-1)&3] (WAR: readers L2@m-3-era + out_duty, gated ✓).
//   No cycles: L2 arrive(m) <- deferred(m-1) <- L1 arrive(m-1) <- L2
//   arrive(m-2) ... strictly decreasing ✓.
//
// Coherence protocol (validated rounds 3-6): slab data sc0/sc1 write-through
// asm ops; vmcnt(0) drain before every arrive; counters via device-scope
// atomicAdd; single-lane sc polls.
// ---------------------------------------------------------------------------

constexpr int Bn = 256;   // batch
constexpr int Tn = 784;   // timesteps
constexpr int Hn = 512;   // hidden
constexpr int Cn = 10;    // classes

typedef short s16x8 __attribute__((ext_vector_type(8)));
typedef float f32x4 __attribute__((ext_vector_type(4)));

__device__ __forceinline__ unsigned short f2bf(float f) {
  unsigned u = __float_as_uint(f);
  u += 0x7FFFu + ((u >> 16) & 1u);  // round-to-nearest-even
  return (unsigned short)(u >> 16);
}
__device__ __forceinline__ float bf2f(unsigned short s) {
  return __uint_as_float(((unsigned)s) << 16);
}
__device__ __forceinline__ float sigm(float v) { return 1.f / (1.f + __expf(-v)); }
__device__ __forceinline__ float tanh_(float v) {
  float vc = fminf(fmaxf(v, -15.f), 15.f);
  float e = __expf(2.f * vc);
  return (e - 1.f) / (e + 1.f);
}

// ---- system-scope (cache-bypassing) accessors ----
__device__ __forceinline__ s16x8 load16_sc(const unsigned short* p) {
  s16x8 r;
  asm volatile("global_load_dwordx4 %0, %1, off sc0 sc1"
               : "=v"(r) : "v"(p) : "memory");
  return r;
}
__device__ __forceinline__ void store2_sc(unsigned short* p, unsigned short v) {
  unsigned w = v;
  asm volatile("global_store_short %0, %1, off sc0 sc1"
               :: "v"(p), "v"(w) : "memory");
}
__device__ __forceinline__ void store4_sc(float* p, float v) {
  asm volatile("global_store_dword %0, %1, off sc0 sc1"
               :: "v"(p), "v"(v) : "memory");
}
// Drain all outstanding vmem (HW counter covers inline-asm ops) + pin sched.
__device__ __forceinline__ void vm0_fence() {
  asm volatile("s_waitcnt vmcnt(0)" ::: "memory");
  __builtin_amdgcn_sched_barrier(0);
}

// ---- counter-based sync (round 6, validated) ----
__device__ __forceinline__ void arrive_cnt(unsigned* p) {
  vm0_fence();
  __syncthreads();
  if (threadIdx.x == 0) atomicAdd(p, 1u);
}
__device__ __forceinline__ void wait2c(const unsigned* pA, int thA,
                                       const unsigned* pB, int thB) {
  if (threadIdx.x == 0 && (thA > 0 || thB > 0)) {
    int guard = 0;
    for (;;) {
      unsigned a, b;
      asm volatile("global_load_dword %0, %2, off sc0 sc1\n\t"
                   "global_load_dword %1, %3, off sc0 sc1\n\t"
                   "s_waitcnt vmcnt(0)"
                   : "=&v"(a), "=&v"(b) : "v"(pA), "v"(pB) : "memory");
      if ((int)a >= thA && (int)b >= thB) break;
      if (++guard > (1 << 20)) break;  // deadlock escape only
      __builtin_amdgcn_s_sleep(1);
    }
  }
  __syncthreads();
}

__global__ void __launch_bounds__(256, 1)
lstm2_kernel(const float* __restrict__ x,
             const float* __restrict__ W_ih1, const float* __restrict__ W_hh1,
             const float* __restrict__ b_ih1, const float* __restrict__ b_hh1,
             const float* __restrict__ W_ih2, const float* __restrict__ W_hh2,
             const float* __restrict__ b_ih2, const float* __restrict__ b_hh2,
             const float* __restrict__ W_fc, const float* __restrict__ b_fc,
             float* __restrict__ out,
             unsigned* __restrict__ cnts,        // per-group counters
             unsigned short* __restrict__ h1b,   // [2][B][H] bf16
             unsigned short* __restrict__ c1b,   // [4][B][H] bf16
             unsigned short* __restrict__ h2b)   // [4][B][H] bf16
{
  extern __shared__ char smem[];
  const int tid = threadIdx.x;
  const int wg = blockIdx.x;
  const int wv = tid >> 6;
  const int l = tid & 63;
  const bool isL1 = (wg < 128);
  const int sub = isL1 ? wg : (wg - 128);
  const int rb = (sub >> 5) << 6;   // 0,64,128,192
  const int js = (sub & 31) << 4;   // 0..496

  // ---- one-time: weight slices -> LDS bf16, XOR-swizzled on 16B chunks ----
  {
    const float* W0 = isL1 ? W_hh1 : W_hh2;
    for (int idx = tid * 4; idx < 64 * 512; idx += 1024) {
      int row = idx >> 9, k = idx & 511;                    // row = g*16 + c
      int n = ((row >> 4) << 9) + js + (row & 15);          // gate col
      float4 w = *(const float4*)(W0 + (size_t)n * Hn + k);
      short4 v = { (short)f2bf(w.x), (short)f2bf(w.y), (short)f2bf(w.z), (short)f2bf(w.w) };
      int byte = (row << 10) + ((((k >> 3) ^ (row & 7)) << 4)) + ((k & 7) << 1);
      *(short4*)(smem + byte) = v;
    }
    if (!isL1) {
      for (int idx = tid * 4; idx < 64 * 512; idx += 1024) {
        int row = idx >> 9, k = idx & 511;
        int n = ((row >> 4) << 9) + js + (row & 15);
        float4 w = *(const float4*)(W_ih2 + (size_t)n * Hn + k);
        short4 v = { (short)f2bf(w.x), (short)f2bf(w.y), (short)f2bf(w.z), (short)f2bf(w.w) };
        int byte = 65536 + (row << 10) + ((((k >> 3) ^ (row & 7)) << 4)) + ((k & 7) << 1);
        *(short4*)(smem + byte) = v;
      }
    } else {
      unsigned short* wf = (unsigned short*)(smem + 65536);
      for (int idx = tid; idx < Cn * Hn; idx += 256) wf[idx] = f2bf(W_fc[idx]);
      if (tid < Cn) ((float*)(smem + 65536 + Cn * Hn * 2))[tid] = b_fc[tid];
    }
  }
  __syncthreads();

  const int rA = l & 15, lg = l >> 4, lx = l & 7;

  // ---- persistent B fragments: my population's recurrent weight slice ----
  // (L1: W_hh1, L2: W_hh2) -- 64 frags = 256 VGPR, loaded once, reused for
  // all 784 phases. Zero LDS reads on the critical path thereafter.
  s16x8 bw[64];
#pragma unroll
  for (int g = 0; g < 4; ++g)
#pragma unroll
    for (int kc = 0; kc < 16; ++kc)
      bw[(g << 4) + kc] =
          *(const s16x8*)(smem + (((g << 4) + rA) << 10) + ((((kc << 2) + lg) ^ lx) << 4));

  // per-lane constants
  float wih1g[4], b1g[4], b2g[4];
  {
    int col = js + rA;
#pragma unroll
    for (int g = 0; g < 4; ++g) {
      int n = (g << 9) + col;
      if (isL1) { wih1g[g] = W_ih1[n]; b1g[g] = b_ih1[n] + b_hh1[n]; b2g[g] = 0.f; }
      else      { wih1g[g] = 0.f;      b1g[g] = 0.f;                 b2g[g] = b_ih2[n] + b_hh2[n]; }
    }
  }

  const int arow = rb + (wv << 4) + rA;           // A-fragment row (batch)
  const int myrow = rb + (wv << 4) + (lg << 2);   // C/D first row (batch)
  const int colj = js + rA;                       // my hidden col

  const int g4 = sub >> 5;
  unsigned* c1p = cnts + g4 * 64;
  unsigned* c2p = cnts + g4 * 64 + 16;

  const size_t SLAB = (size_t)Bn * Hn;
  float cst[4] = {0.f, 0.f, 0.f, 0.f};  // persistent cell state (c1 or c2)

  if (isL1) {
    const int b = (sub << 1) + (wv >> 1);   // out_duty batch row
    const int cg = (wv & 1) * 5;            // out_duty class group
    for (int k = 0; k <= Tn + 2; ++k) {
      wait2c(c1p, k << 5, c2p, (k - 1) << 5);
      s16x8 h8;
      if (k >= 3)   // issue early; retired by arrive's drain, consumed after
        h8 = load16_sc(h2b + (size_t)((k - 3) & 3) * SLAB + (size_t)b * Hn + (l << 3));
      if (k < Tn) {
        float xv[4];
#pragma unroll
        for (int r = 0; r < 4; ++r) xv[r] = x[(size_t)(myrow + r) * Tn + k];
        s16x8 af[16];
        const unsigned short* Ab =
            h1b + (size_t)((k - 1) & 1) * SLAB + (size_t)arow * Hn + (lg << 3);
#pragma unroll
        for (int kc = 0; kc < 16; ++kc) af[kc] = load16_sc(Ab + kc * 32);
        vm0_fence();
        f32x4 acc[4];
#pragma unroll
        for (int g = 0; g < 4; ++g) acc[g] = f32x4{0.f, 0.f, 0.f, 0.f};
#pragma unroll
        for (int kc = 0; kc < 16; ++kc)
#pragma unroll
          for (int g = 0; g < 4; ++g)
            acc[g] = __builtin_amdgcn_mfma_f32_16x16x32_bf16(af[kc], bw[(g << 4) + kc], acc[g], 0, 0, 0);
        unsigned short* h1w = h1b + (size_t)(k & 1) * SLAB;
        unsigned short* c1w = c1b + (size_t)(k & 3) * SLAB;
#pragma unroll
        for (int r = 0; r < 4; ++r) {
          float iv = sigm(acc[0][r] + xv[r] * wih1g[0] + b1g[0]);
          float ff = sigm(acc[1][r] + xv[r] * wih1g[1] + b1g[1]);
          float gv = tanh_(acc[2][r] + xv[r] * wih1g[2] + b1g[2]);
          float ov = sigm(acc[3][r] + xv[r] * wih1g[3] + b1g[3]);
          float c = ff * cst[r] + iv * gv;
          cst[r] = c;
          float h = ov * tanh_(c);
          size_t off = (size_t)(myrow + r) * Hn + colj;
          store2_sc(h1w + off, f2bf(h));
          store2_sc(c1w + off, f2bf(c));
        }
      }
      arrive_cnt(c1p);
      if (k >= 3) {
        // FC for t=k-3 using preloaded h8 (off the critical chain)
        const unsigned short* wf = (const unsigned short*)(smem + 65536);
        float rs[5];
#pragma unroll
        for (int c5 = 0; c5 < 5; ++c5) {
          s16x8 w8 = *(const s16x8*)(wf + (size_t)(cg + c5) * Hn + (l << 3));
          float s = 0.f;
#pragma unroll
          for (int i = 0; i < 8; ++i)
            s += bf2f((unsigned short)h8[i]) * bf2f((unsigned short)w8[i]);
          rs[c5] = s;
        }
#pragma unroll
        for (int c5 = 0; c5 < 5; ++c5) {
#pragma unroll
          for (int off = 32; off > 0; off >>= 1)
            rs[c5] += __shfl_xor(rs[c5], off);
        }
        if (l < 5) {
          float v = (l == 0) ? rs[0] : (l == 1) ? rs[1] : (l == 2) ? rs[2] : (l == 3) ? rs[3] : rs[4];
          v += ((const float*)(smem + 65536 + Cn * Hn * 2))[cg + l];
          store4_sc(out + (size_t)b * (Tn * Cn) + (size_t)(k - 3) * Cn + (cg + l), v);
        }
      }
    }
  } else {
    f32x4 p2[4];  // deferred pre-projection pre2 = c1(t)@W_ih2^T (registers)
#pragma unroll
    for (int g = 0; g < 4; ++g) p2[g] = f32x4{0.f, 0.f, 0.f, 0.f};
    for (int m = 0; m <= Tn + 1; ++m) {
      wait2c(c2p, m << 5, c1p, m << 5);
      if (m >= 1 && m <= Tn) {
        // ---- critical: h2(t=m-1) = cell( h2(m-2)@W_hh2^T + p2 + b2 ) ----
        s16x8 af[16];
        const unsigned short* Ab =
            h2b + (size_t)((m - 2) & 3) * SLAB + (size_t)arow * Hn + (lg << 3);
#pragma unroll
        for (int kc = 0; kc < 16; ++kc) af[kc] = load16_sc(Ab + kc * 32);
        vm0_fence();
        f32x4 acc[4];
#pragma unroll
        for (int g = 0; g < 4; ++g) acc[g] = f32x4{0.f, 0.f, 0.f, 0.f};
#pragma unroll
        for (int kc = 0; kc < 16; ++kc)
#pragma unroll
          for (int g = 0; g < 4; ++g)
            acc[g] = __builtin_amdgcn_mfma_f32_16x16x32_bf16(af[kc], bw[(g << 4) + kc], acc[g], 0, 0, 0);
        unsigned short* h2w = h2b + (size_t)((m - 1) & 3) * SLAB;
#pragma unroll
        for (int r = 0; r < 4; ++r) {
          float iv = sigm(acc[0][r] + p2[0][r] + b2g[0]);
          float ff = sigm(acc[1][r] + p2[1][r] + b2g[1]);
          float gv = tanh_(acc[2][r] + p2[2][r] + b2g[2]);
          float ov = sigm(acc[3][r] + p2[3][r] + b2g[3]);
          float c = ff * cst[r] + iv * gv;
          cst[r] = c;
          float h = ov * tanh_(c);
          store2_sc(h2w + (size_t)(myrow + r) * Hn + colj, f2bf(h));
        }
      }
      arrive_cnt(c2p);
      if (m < Tn) {
        // ---- deferred: p2 = c1(m)@W_ih2^T for next phase (off-chain) ----
        wait2c(c1p, (m + 1) << 5, c1p, 0);  // L1 runs ahead: usually instant
        s16x8 af[16];
        const unsigned short* Ab =
            c1b + (size_t)(m & 3) * SLAB + (size_t)arow * Hn + (lg << 3);
#pragma unroll
        for (int kc = 0; kc < 16; ++kc) af[kc] = load16_sc(Ab + kc * 32);
        vm0_fence();
#pragma unroll
        for (int g = 0; g < 4; ++g) p2[g] = f32x4{0.f, 0.f, 0.f, 0.f};
#pragma unroll
        for (int kc = 0; kc < 16; ++kc)
#pragma unroll
          for (int g = 0; g < 4; ++g) {
            int byte = 65536 + (((g << 4) + rA) << 10) + ((((kc << 2) + lg) ^ lx) << 4);
            p2[g] = __builtin_amdgcn_mfma_f32_16x16x32_bf16(af[kc], *(const s16x8*)(smem + byte), p2[g], 0, 0, 0);
          }
      }
    }
  }
}

extern "C" void kernel_launch(void* const* d_in, const int* in_sizes, int n_in,
                              void* d_out, int out_size, void* d_ws, size_t ws_size,
                              hipStream_t stream) {
  const float* x     = (const float*)d_in[0];
  const float* W_ih1 = (const float*)d_in[1];
  const float* W_hh1 = (const float*)d_in[2];
  const float* b_ih1 = (const float*)d_in[3];
  const float* b_hh1 = (const float*)d_in[4];
  const float* W_ih2 = (const float*)d_in[5];
  const float* W_hh2 = (const float*)d_in[6];
  const float* b_ih2 = (const float*)d_in[7];
  const float* b_hh2 = (const float*)d_in[8];
  const float* W_fc  = (const float*)d_in[9];
  const float* b_fc  = (const float*)d_in[10];
  float* out = (float*)d_out;

  unsigned* cnts = (unsigned*)d_ws;
  unsigned short* h1b = (unsigned short*)((char*)d_ws + 4096);
  unsigned short* c1b = h1b + (size_t)2 * Bn * Hn;
  unsigned short* h2b = c1b + (size_t)4 * Bn * Hn;

  // zero counters + state slabs every launch (graph-replay safe)
  size_t zbytes = 4096 + (size_t)(2 + 4 + 4) * Bn * Hn * sizeof(unsigned short);
  hipMemsetAsync(d_ws, 0, zbytes, stream);

  (void)hipFuncSetAttribute((const void*)lstm2_kernel,
                            hipFuncAttributeMaxDynamicSharedMemorySize, 131072);

  lstm2_kernel<<<dim3(256), dim3(256), 131072, stream>>>(
      x, W_ih1, W_hh1, b_ih1, b_hh1, W_ih2, W_hh2, b_ih2, b_hh2, W_fc, b_fc,
      out, cnts, h1b, c1b, h2b);
}

// Round 8
// 7086.382 us; speedup vs baseline: 1.2602x; 1.0054x over previous
//
#include <hip/hip_runtime.h>

// ---------------------------------------------------------------------------
// 2-layer LSTM (B=256, T=784, H=512, C=10), persistent kernel, round 8.
//
// Round-7 post-mortem: reg-hoisted weights helped (8.9->7.1ms) but floor is
// ~9us/phase vs ~1.5us of chain compute. Dominant residual: sc0/sc1 bypass
// A-operand reads -- 24MB/phase forced to the MALL (32x read amplification
// per stripe) with hard vmcnt(0) joins. Sync redesigns couldn't touch it.
//
// Round-8: XCD-local data paths via measured placement.
//   - 128KiB LDS + grid=256 => exactly 1 WG/CU => exactly 32 WGs/XCD.
//   - Each WG reads HW_REG_XCC_ID (m09: returns 0..7) + atomic rank-grab
//     -> XCD x = stripe s=x>>1 (64 batch rows), role x&1 (L1/L2 pop).
//   - h1 (L1-pop internal) / h2 (L2-pop internal): plain stores (home L2) +
//     sc0-only loads (L1-bypass, L2-hit ~200cyc, no MALL BW). Same-XCD by
//     construction (group = WGs that measured the same XCC_ID).
//   - Cross-XCD only: c1 (L1->L2) and h2fc (small dup of h2 for L1's FC
//     duty, 2 rows/WG) via the validated sc0/sc1 MALL path.
//   - L2's two waits merged at phase top (threshold cnt1>=32(m+1), strictly
//     stronger than r7's split waits -> same dependency graph); c1 loads
//     issue at phase top, overlapping the recurrent gemm.
//
// Schedule (same as round 7, re-audited):
//   L1@k: wait{cnt1>=32k, cnt2>=32(k-1)}; issue h8=h2fc[(k-3)&3] load;
//         G1(k): A=h1[(k-1)&1] (sc0), B=W_hh1 (regs); cell1;
//         store h1[k&1] (plain), c1[k&3] (sc); arrive cnt1; FC-out(k-3).
//   L2@m: wait{cnt2>=32m, cnt1>=32(m+1)}; issue cf=c1[m&3] loads (sc);
//         crit: A=h2[(m-2)&3] (sc0), B=W_hh2 (regs); cell2 w/ p2(m-1);
//         store h2[(m-1)&3] (plain) + h2fc (sc); arrive cnt2;
//         deferred: p2(m) = cf @ W_ih2^T (LDS B).
//   WAR/RAW audit carries from r7 (c1 4-deep: overwrite @k gated by
//   cnt2>=32(k-1) >= phase k-2 done >> top-loads of k-4; h2fc overwrite @m
//   gated by cnt1>=32(m+1) => out_duty h8-load of phase m-2 done; h2 2-deep
//   sufficient but kept 4-deep).
// ---------------------------------------------------------------------------

constexpr int Bn = 256;   // batch
constexpr int Tn = 784;   // timesteps
constexpr int Hn = 512;   // hidden
constexpr int Cn = 10;    // classes

typedef short s16x8 __attribute__((ext_vector_type(8)));
typedef float f32x4 __attribute__((ext_vector_type(4)));

__device__ __forceinline__ unsigned short f2bf(float f) {
  unsigned u = __float_as_uint(f);
  u += 0x7FFFu + ((u >> 16) & 1u);  // round-to-nearest-even
  return (unsigned short)(u >> 16);
}
__device__ __forceinline__ float bf2f(unsigned short s) {
  return __uint_as_float(((unsigned)s) << 16);
}
__device__ __forceinline__ float sigm(float v) { return 1.f / (1.f + __expf(-v)); }
__device__ __forceinline__ float tanh_(float v) {
  float vc = fminf(fmaxf(v, -15.f), 15.f);
  float e = __expf(2.f * vc);
  return (e - 1.f) / (e + 1.f);
}

// ---- accessors ----
// cross-XCD (MALL, cache-bypass, validated r3-r7)
__device__ __forceinline__ s16x8 load16_sc(const unsigned short* p) {
  s16x8 r;
  asm volatile("global_load_dwordx4 %0, %1, off sc0 sc1"
               : "=v"(r) : "v"(p) : "memory");
  return r;
}
__device__ __forceinline__ void store2_sc(unsigned short* p, unsigned short v) {
  unsigned w = v;
  asm volatile("global_store_short %0, %1, off sc0 sc1"
               :: "v"(p), "v"(w) : "memory");
}
// intra-XCD (home-L2 resident; sc0 = bypass own L1 only)
__device__ __forceinline__ s16x8 load16_l2(const unsigned short* p) {
  s16x8 r;
  asm volatile("global_load_dwordx4 %0, %1, off sc0"
               : "=v"(r) : "v"(p) : "memory");
  return r;
}
__device__ __forceinline__ void store2_l2(unsigned short* p, unsigned short v) {
  unsigned w = v;
  asm volatile("global_store_short %0, %1, off"
               :: "v"(p), "v"(w) : "memory");
}
__device__ __forceinline__ void vm0_fence() {
  asm volatile("s_waitcnt vmcnt(0)" ::: "memory");
  __builtin_amdgcn_sched_barrier(0);
}

// ---- counter sync (r6/r7, validated) ----
__device__ __forceinline__ void arrive_cnt(unsigned* p) {
  vm0_fence();      // all data stores committed (L2 for plain, MALL for sc)
  __syncthreads();
  if (threadIdx.x == 0) atomicAdd(p, 1u);   // device-scope, lands at MALL
}
__device__ __forceinline__ void wait2c(const unsigned* pA, int thA,
                                       const unsigned* pB, int thB) {
  if (threadIdx.x == 0 && (thA > 0 || thB > 0)) {
    int guard = 0;
    for (;;) {
      unsigned a, b;
      asm volatile("global_load_dword %0, %2, off sc0 sc1\n\t"
                   "global_load_dword %1, %3, off sc0 sc1\n\t"
                   "s_waitcnt vmcnt(0)"
                   : "=&v"(a), "=&v"(b) : "v"(pA), "v"(pB) : "memory");
      if ((int)a >= thA && (int)b >= thB) break;
      if (++guard > (1 << 20)) break;  // deadlock escape only
      __builtin_amdgcn_s_sleep(1);
    }
  }
  __syncthreads();
}

__global__ void __launch_bounds__(256, 1)
lstm2_kernel(const float* __restrict__ x,
             const float* __restrict__ W_ih1, const float* __restrict__ W_hh1,
             const float* __restrict__ b_ih1, const float* __restrict__ b_hh1,
             const float* __restrict__ W_ih2, const float* __restrict__ W_hh2,
             const float* __restrict__ b_ih2, const float* __restrict__ b_hh2,
             const float* __restrict__ W_fc, const float* __restrict__ b_fc,
             float* __restrict__ out,
             unsigned* __restrict__ cnts,        // counters + rank-grab
             unsigned short* __restrict__ h1b,   // [2][B][H] bf16 (intra)
             unsigned short* __restrict__ c1b,   // [4][B][H] bf16 (cross)
             unsigned short* __restrict__ h2b,   // [4][B][H] bf16 (intra)
             unsigned short* __restrict__ h2fc)  // [4][B][H] bf16 (cross dup)
{
  extern __shared__ char smem[];
  const int tid = threadIdx.x;
  const int wv = tid >> 6;
  const int l = tid & 63;

  // ---- XCD discovery + rank grab (group = WGs sharing a measured XCD) ----
  if (tid == 0) {
    unsigned xcc;
    asm volatile("s_getreg_b32 %0, hwreg(HW_REG_XCC_ID)" : "=s"(xcc));
    xcc &= 7u;
    unsigned rk = atomicAdd(&cnts[256 + xcc], 1u);
    *(unsigned*)(smem + 131064) = xcc;
    *(unsigned*)(smem + 131060) = rk;
  }
  __syncthreads();
  const int xcc  = (int)*(const unsigned*)(smem + 131064);
  const int rank = (int)(*(const unsigned*)(smem + 131060) & 31u);
  const bool isL1 = (xcc & 1) == 0;
  const int s4 = xcc >> 1;          // stripe 0..3
  const int rb = s4 << 6;           // 64-row batch stripe
  const int js = rank << 4;         // 16-col hidden slice

  // ---- one-time: weight slices -> LDS bf16, XOR-swizzled on 16B chunks ----
  {
    const float* W0 = isL1 ? W_hh1 : W_hh2;
    for (int idx = tid * 4; idx < 64 * 512; idx += 1024) {
      int row = idx >> 9, k = idx & 511;                    // row = g*16 + c
      int n = ((row >> 4) << 9) + js + (row & 15);          // gate col
      float4 w = *(const float4*)(W0 + (size_t)n * Hn + k);
      short4 v = { (short)f2bf(w.x), (short)f2bf(w.y), (short)f2bf(w.z), (short)f2bf(w.w) };
      int byte = (row << 10) + ((((k >> 3) ^ (row & 7)) << 4)) + ((k & 7) << 1);
      *(short4*)(smem + byte) = v;
    }
    if (!isL1) {
      for (int idx = tid * 4; idx < 64 * 512; idx += 1024) {
        int row = idx >> 9, k = idx & 511;
        int n = ((row >> 4) << 9) + js + (row & 15);
        float4 w = *(const float4*)(W_ih2 + (size_t)n * Hn + k);
        short4 v = { (short)f2bf(w.x), (short)f2bf(w.y), (short)f2bf(w.z), (short)f2bf(w.w) };
        int byte = 65536 + (row << 10) + ((((k >> 3) ^ (row & 7)) << 4)) + ((k & 7) << 1);
        *(short4*)(smem + byte) = v;
      }
    } else {
      unsigned short* wf = (unsigned short*)(smem + 65536);
      for (int idx = tid; idx < Cn * Hn; idx += 256) wf[idx] = f2bf(W_fc[idx]);
      if (tid < Cn) ((float*)(smem + 65536 + Cn * Hn * 2))[tid] = b_fc[tid];
    }
  }
  __syncthreads();

  const int rA = l & 15, lg = l >> 4, lx = l & 7;

  // persistent recurrent-weight fragments (W_hh1 or W_hh2): 64 frags
  s16x8 bw[64];
#pragma unroll
  for (int g = 0; g < 4; ++g)
#pragma unroll
    for (int kc = 0; kc < 16; ++kc)
      bw[(g << 4) + kc] =
          *(const s16x8*)(smem + (((g << 4) + rA) << 10) + ((((kc << 2) + lg) ^ lx) << 4));

  // per-lane constants
  float wih1g[4], b1g[4], b2g[4];
  {
    int col = js + rA;
#pragma unroll
    for (int g = 0; g < 4; ++g) {
      int n = (g << 9) + col;
      if (isL1) { wih1g[g] = W_ih1[n]; b1g[g] = b_ih1[n] + b_hh1[n]; b2g[g] = 0.f; }
      else      { wih1g[g] = 0.f;      b1g[g] = 0.f;                 b2g[g] = b_ih2[n] + b_hh2[n]; }
    }
  }

  const int arow = rb + (wv << 4) + rA;           // A-fragment row (batch)
  const int myrow = rb + (wv << 4) + (lg << 2);   // C/D first row (batch)
  const int colj = js + rA;                       // my hidden col

  unsigned* c1p = cnts + s4 * 64;        // L1-pop arrivals (stripe-local)
  unsigned* c2p = cnts + s4 * 64 + 16;   // L2-pop arrivals

  const size_t SLAB = (size_t)Bn * Hn;
  float cst[4] = {0.f, 0.f, 0.f, 0.f};

  if (isL1) {
    const int b = rb + (rank << 1) + (wv >> 1);   // FC batch row (2 per WG)
    const int cg = (wv & 1) * 5;                  // FC class group
    for (int k = 0; k <= Tn + 2; ++k) {
      wait2c(c1p, k << 5, c2p, (k - 1) << 5);
      s16x8 h8;
      if (k >= 3)   // cross-XCD dup slab; retired by arrive's drain
        h8 = load16_sc(h2fc + (size_t)((k - 3) & 3) * SLAB + (size_t)b * Hn + (l << 3));
      if (k < Tn) {
        float xv[4];
#pragma unroll
        for (int r = 0; r < 4; ++r) xv[r] = x[(size_t)(myrow + r) * Tn + k];
        s16x8 af[16];
        const unsigned short* Ab =
            h1b + (size_t)((k - 1) & 1) * SLAB + (size_t)arow * Hn + (lg << 3);
#pragma unroll
        for (int kc = 0; kc < 16; ++kc) af[kc] = load16_l2(Ab + kc * 32);
        vm0_fence();
        f32x4 acc[4];
#pragma unroll
        for (int g = 0; g < 4; ++g) acc[g] = f32x4{0.f, 0.f, 0.f, 0.f};
#pragma unroll
        for (int kc = 0; kc < 16; ++kc)
#pragma unroll
          for (int g = 0; g < 4; ++g)
            acc[g] = __builtin_amdgcn_mfma_f32_16x16x32_bf16(af[kc], bw[(g << 4) + kc], acc[g], 0, 0, 0);
        unsigned short* h1w = h1b + (size_t)(k & 1) * SLAB;
        unsigned short* c1w = c1b + (size_t)(k & 3) * SLAB;
#pragma unroll
        for (int r = 0; r < 4; ++r) {
          float iv = sigm(acc[0][r] + xv[r] * wih1g[0] + b1g[0]);
          float ff = sigm(acc[1][r] + xv[r] * wih1g[1] + b1g[1]);
          float gv = tanh_(acc[2][r] + xv[r] * wih1g[2] + b1g[2]);
          float ov = sigm(acc[3][r] + xv[r] * wih1g[3] + b1g[3]);
          float c = ff * cst[r] + iv * gv;
          cst[r] = c;
          float h = ov * tanh_(c);
          size_t off = (size_t)(myrow + r) * Hn + colj;
          store2_l2(h1w + off, f2bf(h));   // intra-XCD
          store2_sc(c1w + off, f2bf(c));   // cross-XCD
        }
      }
      arrive_cnt(c1p);
      if (k >= 3) {   // FC for t=k-3 (off-chain, after arrive)
        const unsigned short* wf = (const unsigned short*)(smem + 65536);
        float rs[5];
#pragma unroll
        for (int c5 = 0; c5 < 5; ++c5) {
          s16x8 w8 = *(const s16x8*)(wf + (size_t)(cg + c5) * Hn + (l << 3));
          float sum = 0.f;
#pragma unroll
          for (int i = 0; i < 8; ++i)
            sum += bf2f((unsigned short)h8[i]) * bf2f((unsigned short)w8[i]);
          rs[c5] = sum;
        }
#pragma unroll
        for (int c5 = 0; c5 < 5; ++c5) {
#pragma unroll
          for (int off = 32; off > 0; off >>= 1)
            rs[c5] += __shfl_xor(rs[c5], off);
        }
        if (l < 5) {
          float v = (l == 0) ? rs[0] : (l == 1) ? rs[1] : (l == 2) ? rs[2] : (l == 3) ? rs[3] : rs[4];
          v += ((const float*)(smem + 65536 + Cn * Hn * 2))[cg + l];
          out[(size_t)b * (Tn * Cn) + (size_t)(k - 3) * Cn + (cg + l)] = v;
        }
      }
    }
  } else {
    f32x4 p2[4];
#pragma unroll
    for (int g = 0; g < 4; ++g) p2[g] = f32x4{0.f, 0.f, 0.f, 0.f};
    for (int m = 0; m <= Tn; ++m) {
      wait2c(c2p, m << 5, c1p, (m + 1) << 5);
      s16x8 cf[16];
      if (m < Tn) {   // c1(m) loads at phase top (cross-XCD), overlap crit
        const unsigned short* Cb =
            c1b + (size_t)(m & 3) * SLAB + (size_t)arow * Hn + (lg << 3);
#pragma unroll
        for (int kc = 0; kc < 16; ++kc) cf[kc] = load16_sc(Cb + kc * 32);
      }
      if (m >= 1) {
        // ---- critical: h2(t=m-1) = cell( h2(m-2)@W_hh2^T + p2 + b2 ) ----
        s16x8 af[16];
        const unsigned short* Ab =
            h2b + (size_t)((m - 2) & 3) * SLAB + (size_t)arow * Hn + (lg << 3);
#pragma unroll
        for (int kc = 0; kc < 16; ++kc) af[kc] = load16_l2(Ab + kc * 32);
        vm0_fence();
        f32x4 acc[4];
#pragma unroll
        for (int g = 0; g < 4; ++g) acc[g] = f32x4{0.f, 0.f, 0.f, 0.f};
#pragma unroll
        for (int kc = 0; kc < 16; ++kc)
#pragma unroll
          for (int g = 0; g < 4; ++g)
            acc[g] = __builtin_amdgcn_mfma_f32_16x16x32_bf16(af[kc], bw[(g << 4) + kc], acc[g], 0, 0, 0);
        unsigned short* h2w  = h2b  + (size_t)((m - 1) & 3) * SLAB;
        unsigned short* h2fw = h2fc + (size_t)((m - 1) & 3) * SLAB;
#pragma unroll
        for (int r = 0; r < 4; ++r) {
          float iv = sigm(acc[0][r] + p2[0][r] + b2g[0]);
          float ff = sigm(acc[1][r] + p2[1][r] + b2g[1]);
          float gv = tanh_(acc[2][r] + p2[2][r] + b2g[2]);
          float ov = sigm(acc[3][r] + p2[3][r] + b2g[3]);
          float c = ff * cst[r] + iv * gv;
          cst[r] = c;
          float h = ov * tanh_(c);
          unsigned short hb = f2bf(h);
          size_t off = (size_t)(myrow + r) * Hn + colj;
          store2_l2(h2w + off, hb);    // intra-XCD (pop-internal reads)
          store2_sc(h2fw + off, hb);   // cross-XCD dup (L1's FC duty)
        }
      }
      arrive_cnt(c2p);
      if (m < Tn) {
        // ---- deferred: p2(m) = c1(m)@W_ih2^T (LDS B), off-chain ----
        vm0_fence();  // cf retired (already drained by arrive; cheap)
#pragma unroll
        for (int g = 0; g < 4; ++g) p2[g] = f32x4{0.f, 0.f, 0.f, 0.f};
#pragma unroll
        for (int kc = 0; kc < 16; ++kc)
#pragma unroll
          for (int g = 0; g < 4; ++g) {
            int byte = 65536 + (((g << 4) + rA) << 10) + ((((kc << 2) + lg) ^ lx) << 4);
            p2[g] = __builtin_amdgcn_mfma_f32_16x16x32_bf16(cf[kc], *(const s16x8*)(smem + byte), p2[g], 0, 0, 0);
          }
      }
    }
  }
}

extern "C" void kernel_launch(void* const* d_in, const int* in_sizes, int n_in,
                              void* d_out, int out_size, void* d_ws, size_t ws_size,
                              hipStream_t stream) {
  const float* x     = (const float*)d_in[0];
  const float* W_ih1 = (const float*)d_in[1];
  const float* W_hh1 = (const float*)d_in[2];
  const float* b_ih1 = (const float*)d_in[3];
  const float* b_hh1 = (const float*)d_in[4];
  const float* W_ih2 = (const float*)d_in[5];
  const float* W_hh2 = (const float*)d_in[6];
  const float* b_ih2 = (const float*)d_in[7];
  const float* b_hh2 = (const float*)d_in[8];
  const float* W_fc  = (const float*)d_in[9];
  const float* b_fc  = (const float*)d_in[10];
  float* out = (float*)d_out;

  unsigned* cnts = (unsigned*)d_ws;
  unsigned short* h1b  = (unsigned short*)((char*)d_ws + 4096);
  unsigned short* c1b  = h1b + (size_t)2 * Bn * Hn;
  unsigned short* h2b  = c1b + (size_t)4 * Bn * Hn;
  unsigned short* h2fc = h2b + (size_t)4 * Bn * Hn;

  // zero counters + rank-grab + state slabs every launch (graph-replay safe)
  size_t zbytes = 4096 + (size_t)(2 + 4 + 4 + 4) * Bn * Hn * sizeof(unsigned short);
  hipMemsetAsync(d_ws, 0, zbytes, stream);

  (void)hipFuncSetAttribute((const void*)lstm2_kernel,
                            hipFuncAttributeMaxDynamicSharedMemorySize, 131072);

  lstm2_kernel<<<dim3(256), dim3(256), 131072, stream>>>(
      x, W_ih1, W_hh1, b_ih1, b_hh1, W_ih2, W_hh2, b_ih2, b_hh2, W_fc, b_fc,
      out, cnts, h1b, c1b, h2b, h2fc);
}

// Round 10
// 5399.018 us; speedup vs baseline: 1.6541x; 1.3125x over previous
//
#include <hip/hip_runtime.h>

// ---------------------------------------------------------------------------
// 2-layer LSTM (B=256, T=784, H=512, C=10), persistent kernel, round 10.
//
// r9 post-mortem: two-tier barrier (3 unproven primitives at once) deadlocked
// -> guard-timeout cascade, garbage. Reverted to r8-proven primitives ONLY.
//
// r10 structural change: STRIPE = XCD. 8 stripes x 32 batch rows; each XCD's
// 32 WGs compute BOTH layers for their rows:
//   waves 0-1: layer-1 (W_hh1 slice in regs), rowfrag = wv.
//   waves 2-3: layer-2 (W_hh2 in regs + W_ih2 from LDS), rowfrag = wv-2.
// Phase k: L1(t=k) || L2(t=k-1) || FC(t=k-2, waves 0-1, after arrive).
// Same-phase slot parity is disjoint: L1 writes h1/c1[k&1]; L2 reads
// c1[(k-1)&1] and h2[(k-2)&1]=h2[k&1](read-only this phase), writes
// h2[(k-1)&1]; FC reads h2[k&1]. -> ONE join per phase.
// Cross-phase RAW/WAR (reuse distance 2) covered by the join: every WG
// vm0-drains its loads/stores before arriving; join at phase k+1 attests
// all phase-k ops retired.
//
// ALL data paths XCD-internal: plain stores (write-through to home L2) +
// sc0 loads (bypass own L1) -- the exact r8-proven intra-XCD RAW pattern.
// The 8 XCDs never exchange data; out rows are stripe-owned.
//
// Sync: one counter per stripe at MALL, HIP atomicAdd (agent scope) after
// vm0_fence + syncthreads; single-lane sc01 poll with s_sleep -- the exact
// r6-r8-proven pattern, but 1 join/phase instead of 2 chained pop-joins.
//
// Phase audit: wait(cnt>=32k) => all 32 WGs finished phase k-1.
//   L1(k) reads h1[(k-1)&1]  <- L1@k-1 ✓; writes h1/c1[k&1], last read @k-1 ✓.
//   L2(k-1) reads c1[(k-1)&1] <- L1@k-1 ✓; reads h2[(k-2)&1] <- L2@k-1 ✓;
//           writes h2[(k-1)&1], last readers (L2 gemm + FC h8) @k-1 ✓.
//   FC(k-2) reads h2[(k-2)&1]=h2[k&1] <- L2@k-1 ✓; that slot is rewritten
//           by L2@k+1, gated by join k+1 >= our arrive(k) > h8 drain ✓.
// ---------------------------------------------------------------------------

constexpr int Bn = 256;   // batch
constexpr int Tn = 784;   // timesteps
constexpr int Hn = 512;   // hidden
constexpr int Cn = 10;    // classes

typedef short s16x8 __attribute__((ext_vector_type(8)));
typedef float f32x4 __attribute__((ext_vector_type(4)));

__device__ __forceinline__ unsigned short f2bf(float f) {
  unsigned u = __float_as_uint(f);
  u += 0x7FFFu + ((u >> 16) & 1u);  // round-to-nearest-even
  return (unsigned short)(u >> 16);
}
__device__ __forceinline__ float bf2f(unsigned short s) {
  return __uint_as_float(((unsigned)s) << 16);
}
__device__ __forceinline__ float sigm(float v) { return 1.f / (1.f + __expf(-v)); }
__device__ __forceinline__ float tanh_(float v) {
  float vc = fminf(fmaxf(v, -15.f), 15.f);
  float e = __expf(2.f * vc);
  return (e - 1.f) / (e + 1.f);
}

// ---- intra-XCD data accessors (r8-proven) ----
__device__ __forceinline__ s16x8 load16_l2(const unsigned short* p) {
  s16x8 r;
  asm volatile("global_load_dwordx4 %0, %1, off sc0"
               : "=v"(r) : "v"(p) : "memory");
  return r;
}
__device__ __forceinline__ void store2_l2(unsigned short* p, unsigned short v) {
  unsigned w = v;
  asm volatile("global_store_short %0, %1, off"
               :: "v"(p), "v"(w) : "memory");
}
__device__ __forceinline__ void vm0_fence() {
  asm volatile("s_waitcnt vmcnt(0)" ::: "memory");
  __builtin_amdgcn_sched_barrier(0);
}
// MALL counter poll (r6-r8-proven)
__device__ __forceinline__ unsigned ld_flag(const unsigned* p) {
  unsigned r;
  asm volatile("global_load_dword %0, %1, off sc0 sc1\n\ts_waitcnt vmcnt(0)"
               : "=v"(r) : "v"(p) : "memory");
  return r;
}

// one-time: weight slice -> LDS bf16, XOR-swizzled on 16B chunks
__device__ __forceinline__ void stage_w(char* smem, const float* W0,
                                        int js, int tid, int base) {
  for (int idx = tid * 4; idx < 64 * 512; idx += 1024) {
    int row = idx >> 9, kk = idx & 511;                   // row = g*16 + c
    int n = ((row >> 4) << 9) + js + (row & 15);          // gate col
    float4 w = *(const float4*)(W0 + (size_t)n * Hn + kk);
    short4 v = { (short)f2bf(w.x), (short)f2bf(w.y), (short)f2bf(w.z), (short)f2bf(w.w) };
    int byte = base + (row << 10) + ((((kk >> 3) ^ (row & 7)) << 4)) + ((kk & 7) << 1);
    *(short4*)(smem + byte) = v;
  }
}

__global__ void __launch_bounds__(256, 1)
lstm2_kernel(const float* __restrict__ x,
             const float* __restrict__ W_ih1, const float* __restrict__ W_hh1,
             const float* __restrict__ b_ih1, const float* __restrict__ b_hh1,
             const float* __restrict__ W_ih2, const float* __restrict__ W_hh2,
             const float* __restrict__ b_ih2, const float* __restrict__ b_hh2,
             const float* __restrict__ W_fc, const float* __restrict__ b_fc,
             float* __restrict__ out,
             unsigned* __restrict__ cnts,        // sync area
             unsigned short* __restrict__ h1b,   // [2][B][H] bf16 (XCD-local)
             unsigned short* __restrict__ c1b,   // [2][B][H] bf16 (XCD-local)
             unsigned short* __restrict__ h2b)   // [2][B][H] bf16 (XCD-local)
{
  extern __shared__ char smem[];
  const int tid = threadIdx.x;
  const int wv = tid >> 6;
  const int l = tid & 63;

  // ---- XCD discovery + rank grab (r8-proven) ----
  if (tid == 0) {
    unsigned xcc;
    asm volatile("s_getreg_b32 %0, hwreg(HW_REG_XCC_ID)" : "=s"(xcc));
    xcc &= 7u;
    unsigned rk = atomicAdd(&cnts[512 + xcc * 16], 1u);
    *(unsigned*)(smem + 131064) = xcc;
    *(unsigned*)(smem + 131060) = rk;
  }
  __syncthreads();
  const int s8   = (int)*(const unsigned*)(smem + 131064);   // stripe = XCD
  const int rank = (int)(*(const unsigned*)(smem + 131060) & 31u);
  const int rb = s8 << 5;           // 32-row batch stripe
  const int js = rank << 4;         // 16-col hidden slice
  unsigned* cnt = cnts + s8 * 64;   // one counter line per stripe

  const int rA = l & 15, lg = l >> 4, lx = l & 7;
  const bool isW1 = (wv < 2);       // waves 0-1: layer-1; waves 2-3: layer-2

  // ---- staged weight load: W_hh1 -> regs(w01), W_hh2 -> regs(w23),
  //      W_ih2 stays in LDS[0..64K), W_fc+b_fc at LDS[64K..) ----
  s16x8 bw[64];
  stage_w(smem, W_hh1, js, tid, 0);
  __syncthreads();
  if (isW1) {
#pragma unroll
    for (int g = 0; g < 4; ++g)
#pragma unroll
      for (int kc = 0; kc < 16; ++kc)
        bw[(g << 4) + kc] =
            *(const s16x8*)(smem + (((g << 4) + rA) << 10) + ((((kc << 2) + lg) ^ lx) << 4));
  }
  __syncthreads();
  stage_w(smem, W_hh2, js, tid, 0);
  __syncthreads();
  if (!isW1) {
#pragma unroll
    for (int g = 0; g < 4; ++g)
#pragma unroll
      for (int kc = 0; kc < 16; ++kc)
        bw[(g << 4) + kc] =
            *(const s16x8*)(smem + (((g << 4) + rA) << 10) + ((((kc << 2) + lg) ^ lx) << 4));
  }
  __syncthreads();
  stage_w(smem, W_ih2, js, tid, 0);
  {
    unsigned short* wf = (unsigned short*)(smem + 65536);
    for (int idx = tid; idx < Cn * Hn; idx += 256) wf[idx] = f2bf(W_fc[idx]);
    if (tid < Cn) ((float*)(smem + 65536 + Cn * Hn * 2))[tid] = b_fc[tid];
  }
  __syncthreads();

  // per-lane constants
  float wih1g[4], bg[4];
  {
    int col = js + rA;
#pragma unroll
    for (int g = 0; g < 4; ++g) {
      int n = (g << 9) + col;
      if (isW1) { wih1g[g] = W_ih1[n]; bg[g] = b_ih1[n] + b_hh1[n]; }
      else      { wih1g[g] = 0.f;      bg[g] = b_ih2[n] + b_hh2[n]; }
    }
  }

  const int rf = isW1 ? wv : (wv - 2);            // rowfrag 0/1
  const int arow  = rb + (rf << 4) + rA;          // A-fragment row (batch)
  const int myrow = rb + (rf << 4) + (lg << 2);   // C/D first row (batch)
  const int colj = js + rA;                       // my hidden col
  const int bfc = rb + rank;                      // FC batch row (1 per WG)
  const int cg = wv * 5;                          // FC class group (wv<2)

  const size_t SLAB = (size_t)Bn * Hn;
  float cst[4] = {0.f, 0.f, 0.f, 0.f};            // c1 (waves 0-1) / c2 (2-3)

  for (int k = 0; k <= Tn + 1; ++k) {
    // ---- single join per phase: all 32 WGs of this stripe ----
    if (tid == 0 && k > 0) {
      int g = 0;
      for (;;) {
        unsigned a = ld_flag(cnt);
        if ((int)a >= (k << 5)) break;
        if (++g > (1 << 20)) break;  // deadlock escape only
        __builtin_amdgcn_s_sleep(1);
      }
    }
    __syncthreads();

    s16x8 h8;
    if (isW1 && k >= 2)   // FC operand h2(k-2), slot (k-2)&1 == k&1
      h8 = load16_l2(h2b + (size_t)(k & 1) * SLAB + (size_t)bfc * Hn + (l << 3));

    if (isW1) {
      // ---------- layer-1 step t=k ----------
      if (k < Tn) {
        float xv[4];
#pragma unroll
        for (int r = 0; r < 4; ++r) xv[r] = x[(size_t)(myrow + r) * Tn + k];
        s16x8 af[16];
        const unsigned short* Ab =
            h1b + (size_t)((k - 1) & 1) * SLAB + (size_t)arow * Hn + (lg << 3);
#pragma unroll
        for (int kc = 0; kc < 16; ++kc) af[kc] = load16_l2(Ab + kc * 32);
        vm0_fence();
        f32x4 acc[4];
#pragma unroll
        for (int g = 0; g < 4; ++g) acc[g] = f32x4{0.f, 0.f, 0.f, 0.f};
#pragma unroll
        for (int kc = 0; kc < 16; ++kc)
#pragma unroll
          for (int g = 0; g < 4; ++g)
            acc[g] = __builtin_amdgcn_mfma_f32_16x16x32_bf16(af[kc], bw[(g << 4) + kc], acc[g], 0, 0, 0);
        unsigned short* h1w = h1b + (size_t)(k & 1) * SLAB;
        unsigned short* c1w = c1b + (size_t)(k & 1) * SLAB;
#pragma unroll
        for (int r = 0; r < 4; ++r) {
          float iv = sigm(acc[0][r] + xv[r] * wih1g[0] + bg[0]);
          float ff = sigm(acc[1][r] + xv[r] * wih1g[1] + bg[1]);
          float gv = tanh_(acc[2][r] + xv[r] * wih1g[2] + bg[2]);
          float ov = sigm(acc[3][r] + xv[r] * wih1g[3] + bg[3]);
          float c = ff * cst[r] + iv * gv;
          cst[r] = c;
          float h = ov * tanh_(c);
          size_t off = (size_t)(myrow + r) * Hn + colj;
          store2_l2(h1w + off, f2bf(h));
          store2_l2(c1w + off, f2bf(c));
        }
      }
    } else {
      // ---------- layer-2 step t=k-1 ----------
      if (k >= 1 && k <= Tn) {
        const int t = k - 1;
        s16x8 af[16], cf[16];
        const unsigned short* Ab =
            h2b + (size_t)((t - 1) & 1) * SLAB + (size_t)arow * Hn + (lg << 3);
        const unsigned short* Cb =
            c1b + (size_t)(t & 1) * SLAB + (size_t)arow * Hn + (lg << 3);
#pragma unroll
        for (int kc = 0; kc < 16; ++kc) af[kc] = load16_l2(Ab + kc * 32);
#pragma unroll
        for (int kc = 0; kc < 16; ++kc) cf[kc] = load16_l2(Cb + kc * 32);
        vm0_fence();
        f32x4 acc[4];
#pragma unroll
        for (int g = 0; g < 4; ++g) acc[g] = f32x4{0.f, 0.f, 0.f, 0.f};
#pragma unroll
        for (int kc = 0; kc < 16; ++kc)
#pragma unroll
          for (int g = 0; g < 4; ++g)
            acc[g] = __builtin_amdgcn_mfma_f32_16x16x32_bf16(af[kc], bw[(g << 4) + kc], acc[g], 0, 0, 0);
#pragma unroll
        for (int kc = 0; kc < 16; ++kc)
#pragma unroll
          for (int g = 0; g < 4; ++g) {
            int byte = (((g << 4) + rA) << 10) + ((((kc << 2) + lg) ^ lx) << 4);
            acc[g] = __builtin_amdgcn_mfma_f32_16x16x32_bf16(cf[kc], *(const s16x8*)(smem + byte), acc[g], 0, 0, 0);
          }
        unsigned short* h2w = h2b + (size_t)(t & 1) * SLAB;
#pragma unroll
        for (int r = 0; r < 4; ++r) {
          float iv = sigm(acc[0][r] + bg[0]);
          float ff = sigm(acc[1][r] + bg[1]);
          float gv = tanh_(acc[2][r] + bg[2]);
          float ov = sigm(acc[3][r] + bg[3]);
          float c = ff * cst[r] + iv * gv;
          cst[r] = c;
          float h = ov * tanh_(c);
          store2_l2(h2w + (size_t)(myrow + r) * Hn + colj, f2bf(h));
        }
      }
    }

    // ---- arrive: drain ALL waves' asm ops, then one MALL atomic ----
    vm0_fence();
    __syncthreads();
    if (tid == 0) atomicAdd(cnt, 1u);

    // ---- FC for t=k-2 (waves 0-1, off the critical chain) ----
    if (isW1 && k >= 2) {
      const unsigned short* wf = (const unsigned short*)(smem + 65536);
      float rs[5];
#pragma unroll
      for (int c5 = 0; c5 < 5; ++c5) {
        s16x8 w8 = *(const s16x8*)(wf + (size_t)(cg + c5) * Hn + (l << 3));
        float sum = 0.f;
#pragma unroll
        for (int i = 0; i < 8; ++i)
          sum += bf2f((unsigned short)h8[i]) * bf2f((unsigned short)w8[i]);
        rs[c5] = sum;
      }
#pragma unroll
      for (int c5 = 0; c5 < 5; ++c5) {
#pragma unroll
        for (int off = 32; off > 0; off >>= 1)
          rs[c5] += __shfl_xor(rs[c5], off);
      }
      if (l < 5) {
        float v = (l == 0) ? rs[0] : (l == 1) ? rs[1] : (l == 2) ? rs[2] : (l == 3) ? rs[3] : rs[4];
        v += ((const float*)(smem + 65536 + Cn * Hn * 2))[cg + l];
        out[(size_t)bfc * (Tn * Cn) + (size_t)(k - 2) * Cn + (cg + l)] = v;
      }
    }
  }
}

extern "C" void kernel_launch(void* const* d_in, const int* in_sizes, int n_in,
                              void* d_out, int out_size, void* d_ws, size_t ws_size,
                              hipStream_t stream) {
  const float* x     = (const float*)d_in[0];
  const float* W_ih1 = (const float*)d_in[1];
  const float* W_hh1 = (const float*)d_in[2];
  const float* b_ih1 = (const float*)d_in[3];
  const float* b_hh1 = (const float*)d_in[4];
  const float* W_ih2 = (const float*)d_in[5];
  const float* W_hh2 = (const float*)d_in[6];
  const float* b_ih2 = (const float*)d_in[7];
  const float* b_hh2 = (const float*)d_in[8];
  const float* W_fc  = (const float*)d_in[9];
  const float* b_fc  = (const float*)d_in[10];
  float* out = (float*)d_out;

  unsigned* cnts = (unsigned*)d_ws;
  unsigned short* h1b = (unsigned short*)((char*)d_ws + 4096);
  unsigned short* c1b = h1b + (size_t)2 * Bn * Hn;
  unsigned short* h2b = c1b + (size_t)2 * Bn * Hn;

  // zero sync area + state slabs every launch (graph-replay safe)
  size_t zbytes = 4096 + (size_t)3 * 2 * Bn * Hn * sizeof(unsigned short);
  hipMemsetAsync(d_ws, 0, zbytes, stream);

  (void)hipFuncSetAttribute((const void*)lstm2_kernel,
                            hipFuncAttributeMaxDynamicSharedMemorySize, 131072);

  lstm2_kernel<<<dim3(256), dim3(256), 131072, stream>>>(
      x, W_ih1, W_hh1, b_ih1, b_hh1, W_ih2, W_hh2, b_ih2, b_hh2, W_fc, b_fc,
      out, cnts, h1b, c1b, h2b);
}

// Round 13
// 4705.535 us; speedup vs baseline: 1.8979x; 1.1474x over previous
//
#include <hip/hip_runtime.h>

// ---------------------------------------------------------------------------
// 2-layer LSTM (B=256, T=784, H=512, C=10), persistent kernel, round 13.
//
// r12 post-mortem: runtime HANG. Join used PLAIN flag stores polled by sc0
// loads; plain-store-as-sync-edge never becomes visible to pollers (r10's
// data path only proved plain->sc0 AFTER a MALL-counter join interposed).
// Rule: flags need proven flag primitives -- sc01 stores+polls (r5) or
// device-scope atomics (r6-r10). Plain stores are data-only, under a sync.
//
// r13 = r10 base (passed, 5.40ms) + two changes:
//  1. Join: 32 per-WG MALL flag words per stripe (2 cache lines).
//     arrive = ONE sc01 store (tid0, after vm0-drain + syncthreads);
//     poll = wave0's 32 lanes sc01-load all flags in parallel + __all
//     -> detection ~1 MALL RTT, no 32-serialized atomicAdd queue.
//  2. Addr-gen: batched 16-load asm blocks (offset: immediates off one
//     parity-selected base) + 4-store blocks (r12-compiled syntax).
//
// r10 topology unchanged: stripe = XCD (r8/r10-proven discovery); 8 stripes
// x 32 batch rows; waves 0-1 layer-1 (W_hh1 regs), waves 2-3 layer-2
// (W_hh2 regs + W_ih2 LDS). Phase k: L1(t=k) || L2(t=k-1) || FC(t=k-2).
// One join/phase. Data intra-XCD: plain stores -> home L2, sc0 loads,
// always read strictly after the MALL-flag join edge (as in r10).
//
// Phase audit (r10): wait(all 32 flags >= k) => all WGs finished k-1.
// L1(k) reads h1[(k-1)&1] ✓, writes h1/c1[k&1] (last read @k-1) ✓;
// L2(k-1) reads c1[(k-1)&1], h2[(k-2)&1], writes h2[(k-1)&1] ✓;
// FC(k-2) reads h2[k&1], rewritten only @k+1 (after our arrive) ✓.
// Every WG vm0-drains (covers asm stores) before its flag store ✓.
// ---------------------------------------------------------------------------

constexpr int Bn = 256;   // batch
constexpr int Tn = 784;   // timesteps
constexpr int Hn = 512;   // hidden
constexpr int Cn = 10;    // classes

typedef short s16x8 __attribute__((ext_vector_type(8)));
typedef float f32x4 __attribute__((ext_vector_type(4)));

__device__ __forceinline__ unsigned short f2bf(float f) {
  unsigned u = __float_as_uint(f);
  u += 0x7FFFu + ((u >> 16) & 1u);  // round-to-nearest-even
  return (unsigned short)(u >> 16);
}
__device__ __forceinline__ float bf2f(unsigned short s) {
  return __uint_as_float(((unsigned)s) << 16);
}
__device__ __forceinline__ float sigm(float v) { return 1.f / (1.f + __expf(-v)); }
__device__ __forceinline__ float tanh_(float v) {
  float vc = fminf(fmaxf(v, -15.f), 15.f);
  float e = __expf(2.f * vc);
  return (e - 1.f) / (e + 1.f);
}

// ---- intra-XCD data accessors (r10-proven classes) ----
__device__ __forceinline__ s16x8 load16_l2(const unsigned short* p) {
  s16x8 r;
  asm volatile("global_load_dwordx4 %0, %1, off sc0"
               : "=v"(r) : "v"(p) : "memory");
  return r;
}
// 16 fragment loads off ONE base pointer, offset immediates (saves 15x 64b adds)
__device__ __forceinline__ void load16x16_l2(const unsigned short* p, s16x8* f) {
  asm volatile(
      "global_load_dwordx4 %0, %16, off sc0\n\t"
      "global_load_dwordx4 %1, %16, off offset:64 sc0\n\t"
      "global_load_dwordx4 %2, %16, off offset:128 sc0\n\t"
      "global_load_dwordx4 %3, %16, off offset:192 sc0\n\t"
      "global_load_dwordx4 %4, %16, off offset:256 sc0\n\t"
      "global_load_dwordx4 %5, %16, off offset:320 sc0\n\t"
      "global_load_dwordx4 %6, %16, off offset:384 sc0\n\t"
      "global_load_dwordx4 %7, %16, off offset:448 sc0\n\t"
      "global_load_dwordx4 %8, %16, off offset:512 sc0\n\t"
      "global_load_dwordx4 %9, %16, off offset:576 sc0\n\t"
      "global_load_dwordx4 %10, %16, off offset:640 sc0\n\t"
      "global_load_dwordx4 %11, %16, off offset:704 sc0\n\t"
      "global_load_dwordx4 %12, %16, off offset:768 sc0\n\t"
      "global_load_dwordx4 %13, %16, off offset:832 sc0\n\t"
      "global_load_dwordx4 %14, %16, off offset:896 sc0\n\t"
      "global_load_dwordx4 %15, %16, off offset:960 sc0"
      : "=&v"(f[0]), "=&v"(f[1]), "=&v"(f[2]), "=&v"(f[3]),
        "=&v"(f[4]), "=&v"(f[5]), "=&v"(f[6]), "=&v"(f[7]),
        "=&v"(f[8]), "=&v"(f[9]), "=&v"(f[10]), "=&v"(f[11]),
        "=&v"(f[12]), "=&v"(f[13]), "=&v"(f[14]), "=&v"(f[15])
      : "v"(p) : "memory");
}
// 4 row-stores (stride Hn*2 = 1024B) off one base
__device__ __forceinline__ void store4_l2(unsigned short* p, unsigned v0,
                                          unsigned v1, unsigned v2, unsigned v3) {
  asm volatile(
      "global_store_short %0, %1, off\n\t"
      "global_store_short %0, %2, off offset:1024\n\t"
      "global_store_short %0, %3, off offset:2048\n\t"
      "global_store_short %0, %4, off offset:3072"
      :: "v"(p), "v"(v0), "v"(v1), "v"(v2), "v"(v3) : "memory");
}
__device__ __forceinline__ void vm0_fence() {
  asm volatile("s_waitcnt vmcnt(0)" ::: "memory");
  __builtin_amdgcn_sched_barrier(0);
}
// ---- MALL flag ops (r5-proven classes: sc01 store + sc01 poll) ----
__device__ __forceinline__ unsigned ld_flag_mall(const unsigned* p) {
  unsigned r;
  asm volatile("global_load_dword %0, %1, off sc0 sc1\n\ts_waitcnt vmcnt(0)"
               : "=v"(r) : "v"(p) : "memory");
  return r;
}
__device__ __forceinline__ void st_flag_mall(unsigned* p, unsigned v) {
  asm volatile("global_store_dword %0, %1, off sc0 sc1"
               :: "v"(p), "v"(v) : "memory");
}

// one-time: weight slice -> LDS bf16, XOR-swizzled on 16B chunks
__device__ __forceinline__ void stage_w(char* smem, const float* W0,
                                        int js, int tid, int base) {
  for (int idx = tid * 4; idx < 64 * 512; idx += 1024) {
    int row = idx >> 9, kk = idx & 511;                   // row = g*16 + c
    int n = ((row >> 4) << 9) + js + (row & 15);          // gate col
    float4 w = *(const float4*)(W0 + (size_t)n * Hn + kk);
    short4 v = { (short)f2bf(w.x), (short)f2bf(w.y), (short)f2bf(w.z), (short)f2bf(w.w) };
    int byte = base + (row << 10) + ((((kk >> 3) ^ (row & 7)) << 4)) + ((kk & 7) << 1);
    *(short4*)(smem + byte) = v;
  }
}

__global__ void __launch_bounds__(256, 1)
lstm2_kernel(const float* __restrict__ x,
             const float* __restrict__ W_ih1, const float* __restrict__ W_hh1,
             const float* __restrict__ b_ih1, const float* __restrict__ b_hh1,
             const float* __restrict__ W_ih2, const float* __restrict__ W_hh2,
             const float* __restrict__ b_ih2, const float* __restrict__ b_hh2,
             const float* __restrict__ W_fc, const float* __restrict__ b_fc,
             float* __restrict__ out,
             unsigned* __restrict__ cnts,        // sync area (32KB)
             unsigned short* __restrict__ h1b,   // [2][B][H] bf16 (XCD-local)
             unsigned short* __restrict__ c1b,   // [2][B][H] bf16 (XCD-local)
             unsigned short* __restrict__ h2b)   // [2][B][H] bf16 (XCD-local)
{
  extern __shared__ char smem[];
  const int tid = threadIdx.x;
  const int wv = tid >> 6;
  const int l = tid & 63;

  // ---- XCD discovery + rank grab (r8/r10-proven) ----
  if (tid == 0) {
    unsigned xcc;
    asm volatile("s_getreg_b32 %0, hwreg(HW_REG_XCC_ID)" : "=s"(xcc));
    xcc &= 7u;
    unsigned rk = atomicAdd(&cnts[512 + xcc * 16], 1u);
    *(unsigned*)(smem + 131064) = xcc;
    *(unsigned*)(smem + 131060) = rk;
  }
  __syncthreads();
  const int s8   = (int)*(const unsigned*)(smem + 131064);   // stripe = XCD
  const int rank = (int)(*(const unsigned*)(smem + 131060) & 31u);
  const int rb = s8 << 5;           // 32-row batch stripe
  const int js = rank << 4;         // 16-col hidden slice

  // flags: 32 contiguous words per stripe (2 cache lines) at 1024 + s8*32
  unsigned* fbase = cnts + 1024 + s8 * 32;
  unsigned* myflag = fbase + rank;

  const int rA = l & 15, lg = l >> 4, lx = l & 7;
  const bool isW1 = (wv < 2);       // waves 0-1: layer-1; waves 2-3: layer-2

  // ---- staged weight load: W_hh1 -> regs(w0-1), W_hh2 -> regs(w2-3),
  //      then W_ih2 -> LDS[0..64K), W_fc+b_fc -> LDS[64K..) ----
  s16x8 bw[64];
  stage_w(smem, W_hh1, js, tid, 0);
  __syncthreads();
  if (isW1) {
#pragma unroll
    for (int g = 0; g < 4; ++g)
#pragma unroll
      for (int kc = 0; kc < 16; ++kc)
        bw[(g << 4) + kc] =
            *(const s16x8*)(smem + (((g << 4) + rA) << 10) + ((((kc << 2) + lg) ^ lx) << 4));
  }
  __syncthreads();
  stage_w(smem, W_hh2, js, tid, 0);
  __syncthreads();
  if (!isW1) {
#pragma unroll
    for (int g = 0; g < 4; ++g)
#pragma unroll
      for (int kc = 0; kc < 16; ++kc)
        bw[(g << 4) + kc] =
            *(const s16x8*)(smem + (((g << 4) + rA) << 10) + ((((kc << 2) + lg) ^ lx) << 4));
  }
  __syncthreads();
  stage_w(smem, W_ih2, js, tid, 0);
  {
    unsigned short* wf = (unsigned short*)(smem + 65536);
    for (int idx = tid; idx < Cn * Hn; idx += 256) wf[idx] = f2bf(W_fc[idx]);
    if (tid < Cn) ((float*)(smem + 65536 + Cn * Hn * 2))[tid] = b_fc[tid];
  }
  __syncthreads();

  // per-lane constants
  float wih1g[4], bg[4];
  {
    int col = js + rA;
#pragma unroll
    for (int g = 0; g < 4; ++g) {
      int n = (g << 9) + col;
      if (isW1) { wih1g[g] = W_ih1[n]; bg[g] = b_ih1[n] + b_hh1[n]; }
      else      { wih1g[g] = 0.f;      bg[g] = b_ih2[n] + b_hh2[n]; }
    }
  }

  const int rf = isW1 ? wv : (wv - 2);            // rowfrag 0/1
  const int arow  = rb + (rf << 4) + rA;          // A-fragment row (batch)
  const int myrow = rb + (rf << 4) + (lg << 2);   // C/D first row (batch)
  const int colj = js + rA;                       // my hidden col
  const int bfc = rb + rank;                      // FC batch row (1 per WG)
  const int cg = wv * 5;                          // FC class group (wv<2)

  const size_t SLAB = (size_t)Bn * Hn;
  // parity-selected base pointers (precomputed; select = 1 cndmask pair)
  const size_t aoff = (size_t)arow * Hn + (lg << 3);
  const unsigned short* h1A0 = h1b + aoff;                 // h1 slab parity 0
  const unsigned short* h1A1 = h1b + SLAB + aoff;
  const unsigned short* h2A0 = h2b + aoff;
  const unsigned short* h2A1 = h2b + SLAB + aoff;
  const unsigned short* c1A0 = c1b + aoff;
  const unsigned short* c1A1 = c1b + SLAB + aoff;
  const size_t woff = (size_t)myrow * Hn + colj;
  unsigned short* h1W0 = h1b + woff;  unsigned short* h1W1 = h1b + SLAB + woff;
  unsigned short* c1W0 = c1b + woff;  unsigned short* c1W1 = c1b + SLAB + woff;
  unsigned short* h2W0 = h2b + woff;  unsigned short* h2W1 = h2b + SLAB + woff;
  const unsigned short* fcA0 = h2b + (size_t)bfc * Hn + (l << 3);
  const unsigned short* fcA1 = fcA0 + SLAB;

  float cst[4] = {0.f, 0.f, 0.f, 0.f};            // c1 (waves 0-1) / c2 (2-3)

  for (int k = 0; k <= Tn + 1; ++k) {
    // ---- single join/phase: wave0's 32 lanes poll the 32 MALL flags ----
    if (wv == 0 && k > 0) {
      const unsigned* p = fbase + (l & 31);
      int g = 0;
      for (;;) {
        unsigned a = ld_flag_mall(p);
        if (__all((int)a >= k)) break;
        if (++g > (1 << 20)) break;  // deadlock escape only
        __builtin_amdgcn_s_sleep(1);
      }
    }
    __syncthreads();

    s16x8 h8;
    if (isW1 && k >= 2)   // FC operand h2(k-2), slot (k-2)&1 == k&1
      h8 = load16_l2((k & 1) ? fcA1 : fcA0);

    if (isW1) {
      // ---------- layer-1 step t=k ----------
      if (k < Tn) {
        float xv[4];
#pragma unroll
        for (int r = 0; r < 4; ++r) xv[r] = x[(size_t)(myrow + r) * Tn + k];
        s16x8 af[16];
        load16x16_l2(((k - 1) & 1) ? h1A1 : h1A0, af);
        vm0_fence();
        f32x4 acc[4];
#pragma unroll
        for (int g = 0; g < 4; ++g) acc[g] = f32x4{0.f, 0.f, 0.f, 0.f};
#pragma unroll
        for (int kc = 0; kc < 16; ++kc)
#pragma unroll
          for (int g = 0; g < 4; ++g)
            acc[g] = __builtin_amdgcn_mfma_f32_16x16x32_bf16(af[kc], bw[(g << 4) + kc], acc[g], 0, 0, 0);
        unsigned hv[4], cv[4];
#pragma unroll
        for (int r = 0; r < 4; ++r) {
          float iv = sigm(acc[0][r] + xv[r] * wih1g[0] + bg[0]);
          float ff = sigm(acc[1][r] + xv[r] * wih1g[1] + bg[1]);
          float gv = tanh_(acc[2][r] + xv[r] * wih1g[2] + bg[2]);
          float ov = sigm(acc[3][r] + xv[r] * wih1g[3] + bg[3]);
          float c = ff * cst[r] + iv * gv;
          cst[r] = c;
          hv[r] = f2bf(ov * tanh_(c));
          cv[r] = f2bf(c);
        }
        store4_l2((k & 1) ? h1W1 : h1W0, hv[0], hv[1], hv[2], hv[3]);
        store4_l2((k & 1) ? c1W1 : c1W0, cv[0], cv[1], cv[2], cv[3]);
      }
    } else {
      // ---------- layer-2 step t=k-1 ----------
      if (k >= 1 && k <= Tn) {
        const int t = k - 1;
        s16x8 af[16], cf[16];
        load16x16_l2(((t - 1) & 1) ? h2A1 : h2A0, af);
        load16x16_l2((t & 1) ? c1A1 : c1A0, cf);
        vm0_fence();
        f32x4 acc[4];
#pragma unroll
        for (int g = 0; g < 4; ++g) acc[g] = f32x4{0.f, 0.f, 0.f, 0.f};
#pragma unroll
        for (int kc = 0; kc < 16; ++kc)
#pragma unroll
          for (int g = 0; g < 4; ++g)
            acc[g] = __builtin_amdgcn_mfma_f32_16x16x32_bf16(af[kc], bw[(g << 4) + kc], acc[g], 0, 0, 0);
#pragma unroll
        for (int kc = 0; kc < 16; ++kc)
#pragma unroll
          for (int g = 0; g < 4; ++g) {
            int byte = (((g << 4) + rA) << 10) + ((((kc << 2) + lg) ^ lx) << 4);
            acc[g] = __builtin_amdgcn_mfma_f32_16x16x32_bf16(cf[kc], *(const s16x8*)(smem + byte), acc[g], 0, 0, 0);
          }
        unsigned hv[4];
#pragma unroll
        for (int r = 0; r < 4; ++r) {
          float iv = sigm(acc[0][r] + bg[0]);
          float ff = sigm(acc[1][r] + bg[1]);
          float gv = tanh_(acc[2][r] + bg[2]);
          float ov = sigm(acc[3][r] + bg[3]);
          float c = ff * cst[r] + iv * gv;
          cst[r] = c;
          hv[r] = f2bf(ov * tanh_(c));
        }
        store4_l2((t & 1) ? h2W1 : h2W0, hv[0], hv[1], hv[2], hv[3]);
      }
    }

    // ---- arrive: drain own vmem (asm ops incl.), sync, one sc01 flag ----
    vm0_fence();
    __syncthreads();
    if (tid == 0) st_flag_mall(myflag, (unsigned)(k + 1));

    // ---- FC for t=k-2 (waves 0-1, off the critical chain) ----
    if (isW1 && k >= 2) {
      const unsigned short* wf = (const unsigned short*)(smem + 65536);
      float rs[5];
#pragma unroll
      for (int c5 = 0; c5 < 5; ++c5) {
        s16x8 w8 = *(const s16x8*)(wf + (size_t)(cg + c5) * Hn + (l << 3));
        float sum = 0.f;
#pragma unroll
        for (int i = 0; i < 8; ++i)
          sum += bf2f((unsigned short)h8[i]) * bf2f((unsigned short)w8[i]);
        rs[c5] = sum;
      }
#pragma unroll
      for (int c5 = 0; c5 < 5; ++c5) {
#pragma unroll
        for (int off = 32; off > 0; off >>= 1)
          rs[c5] += __shfl_xor(rs[c5], off);
      }
      if (l < 5) {
        float v = (l == 0) ? rs[0] : (l == 1) ? rs[1] : (l == 2) ? rs[2] : (l == 3) ? rs[3] : rs[4];
        v += ((const float*)(smem + 65536 + Cn * Hn * 2))[cg + l];
        out[(size_t)bfc * (Tn * Cn) + (size_t)(k - 2) * Cn + (cg + l)] = v;
      }
    }
  }
}

extern "C" void kernel_launch(void* const* d_in, const int* in_sizes, int n_in,
                              void* d_out, int out_size, void* d_ws, size_t ws_size,
                              hipStream_t stream) {
  const float* x     = (const float*)d_in[0];
  const float* W_ih1 = (const float*)d_in[1];
  const float* W_hh1 = (const float*)d_in[2];
  const float* b_ih1 = (const float*)d_in[3];
  const float* b_hh1 = (const float*)d_in[4];
  const float* W_ih2 = (const float*)d_in[5];
  const float* W_hh2 = (const float*)d_in[6];
  const float* b_ih2 = (const float*)d_in[7];
  const float* b_hh2 = (const float*)d_in[8];
  const float* W_fc  = (const float*)d_in[9];
  const float* b_fc  = (const float*)d_in[10];
  float* out = (float*)d_out;

  unsigned* cnts = (unsigned*)d_ws;
  unsigned short* h1b = (unsigned short*)((char*)d_ws + 32768);
  unsigned short* c1b = h1b + (size_t)2 * Bn * Hn;
  unsigned short* h2b = c1b + (size_t)2 * Bn * Hn;

  // zero sync area (rank-grab + flags) + state slabs every launch
  size_t zbytes = 32768 + (size_t)3 * 2 * Bn * Hn * sizeof(unsigned short);
  hipMemsetAsync(d_ws, 0, zbytes, stream);

  (void)hipFuncSetAttribute((const void*)lstm2_kernel,
                            hipFuncAttributeMaxDynamicSharedMemorySize, 131072);

  lstm2_kernel<<<dim3(256), dim3(256), 131072, stream>>>(
      x, W_ih1, W_hh1, b_ih1, b_hh1, W_ih2, W_hh2, b_ih2, b_hh2, W_fc, b_fc,
      out, cnts, h1b, c1b, h2b);
}